// Round 6
// baseline (87.829 us; speedup 1.0000x reference)
//
#include <hip/hip_runtime.h>
#include <hip/hip_bf16.h>

// ConvexWidthUpsampler: VALU conv3x3 (z) + MFMA [M1|bias|M2]·[xv,1,|z|]
// + softmax + convex combine.  R4-proven structure; LDS rows 128B with
// XOR block swizzle (block ^= row&7) -> conflict-free, 5 blocks/CU.
// B=16,C=1,H=512,W=512,up=(1,3). Output [16,1,512,1536] f32.

#define BB 16
#define HH 512
#define WW 512
#define HID 32
#define NM 27
#define LOG2E 1.44269504088896340736f

typedef short bf16x8 __attribute__((ext_vector_type(8)));
typedef float f32x4  __attribute__((ext_vector_type(4)));
typedef unsigned int u32;
typedef u32 u32x4 __attribute__((ext_vector_type(4)));

__device__ __forceinline__ u32 pk2(float a, float b) {
    union { __hip_bfloat162 h2; u32 u; } cv;
    cv.h2 = __float22bfloat162_rn(make_float2(a, b));
    return cv.u;
}

// ---------------- prep: build B matrix [2 terms][32 n][64 k] bf16 ----------
// (identical to R4 — proven across graph replays)
__global__ void prep_B(const float* __restrict__ w1, const float* __restrict__ b1,
                       const float* __restrict__ alpha, const float* __restrict__ w2,
                       const float* __restrict__ b2, __hip_bfloat16* __restrict__ wsB) {
    const int i = blockIdx.x * 256 + threadIdx.x;   // 0..2047
    if (i >= 2048) return;
    const int n = i >> 6, k = i & 63;
    float v = 0.0f;
    if (n < NM) {
        if (k < 9) {
            for (int c = 0; c < HID; ++c)
                v += w2[n * HID + c] * (0.5f * (1.0f + alpha[c])) * w1[c * 9 + k];
        } else if (k == 9) {
            v = b2[n];
            for (int c = 0; c < HID; ++c)
                v += w2[n * HID + c] * (0.5f * (1.0f + alpha[c])) * b1[c];
        } else if (k >= 16 && k < 48) {
            const int c = k - 16;
            v = w2[n * HID + c] * (0.5f * (1.0f - alpha[c]));
        }
    }
    v *= LOG2E;
    const __hip_bfloat16 hi = __float2bfloat16(v);
    const __hip_bfloat16 lo = __float2bfloat16(v - __bfloat162float(hi));
    wsB[n * 64 + k]        = hi;   // term 0
    wsB[2048 + n * 64 + k] = lo;   // term 1
}

// ---------------- main fused kernel ----------------------------------------
__global__ __launch_bounds__(256, 5) void convex_upsample_mfma(
    const float* __restrict__ x,      // [16,1,512,512]
    const float* __restrict__ w1,     // [32,9] f32
    const float* __restrict__ b1,     // [32] f32
    const __hip_bfloat16* __restrict__ wsB, // [2][32][64] bf16
    float* __restrict__ out)          // [16,1,512,1536]
{
    __shared__ char lds_raw[4][64 * 128];   // 32768 B -> 5 blocks/CU

    const int tid  = threadIdx.x;
    const int wv   = tid >> 6;
    const int lane = tid & 63;
    const int l16  = lane & 15;
    const int lq   = lane >> 4;
    char* wbase = lds_raw[wv];

    const int p    = blockIdx.x * 256 + tid;
    const int wcol = p & (WW - 1);
    const int t    = p >> 9;
    const int hrow = t & (HH - 1);
    const int bidx = t >> 9;

    // B fragments: lane holds col n = nt*16+l16, k = kt*32 + lq*8 + i
    bf16x8 Bf[2][2][2];   // [term][kt][nt]
#pragma unroll
    for (int tm = 0; tm < 2; ++tm)
#pragma unroll
        for (int nt = 0; nt < 2; ++nt)
#pragma unroll
            for (int kt = 0; kt < 2; ++kt)
                Bf[tm][kt][nt] = *(const bf16x8*)(wsB + tm * 2048 + (nt * 16 + l16) * 64 + kt * 32 + lq * 8);

    // 3x3 neighborhood, zero padded
    const float* xb = x + (size_t)bidx * (HH * WW);
    float xv[9];
#pragma unroll
    for (int ki = 0; ki < 3; ++ki) {
        const int hy = hrow + ki - 1;
        const bool hok = (unsigned)hy < (unsigned)HH;
#pragma unroll
        for (int kj = 0; kj < 3; ++kj) {
            const int wx = wcol + kj - 1;
            const bool ok = hok && ((unsigned)wx < (unsigned)WW);
            xv[ki * 3 + kj] = ok ? xb[hy * WW + wx] : 0.0f;
        }
    }

    // write A row (swizzled): k0..8=xv, k9=1.0, k10..15=0, |z| k16..47, 0 k48..63
    const int sx = (lane & 7) << 4;
    char* myrow = wbase + lane * 128;
    *(u32x4*)(myrow + (0 ^ sx))  = (u32x4){pk2(xv[0], xv[1]), pk2(xv[2], xv[3]),
                                           pk2(xv[4], xv[5]), pk2(xv[6], xv[7])};
    *(u32x4*)(myrow + (16 ^ sx)) = (u32x4){pk2(xv[8], 1.0f), 0u, 0u, 0u};

    // z = W1*xv + b1 (f32 VALU), |z| -> bf16 pairs -> k16..47 (bytes 32..95)
#pragma unroll
    for (int q = 0; q < 4; ++q) {
        u32 d[4];
#pragma unroll
        for (int h = 0; h < 4; ++h) {
            const int c0 = q * 8 + h * 2;
            float za = b1[c0], zb = b1[c0 + 1];
#pragma unroll
            for (int k = 0; k < 9; ++k) {
                za = fmaf(w1[c0 * 9 + k], xv[k], za);
                zb = fmaf(w1[(c0 + 1) * 9 + k], xv[k], zb);
            }
            d[h] = pk2(fabsf(za), fabsf(zb));
        }
        *(u32x4*)(myrow + ((32 + q * 16) ^ sx)) = (u32x4){d[0], d[1], d[2], d[3]};
    }
    *(u32x4*)(myrow + (96 ^ sx))  = (u32x4){0u, 0u, 0u, 0u};
    *(u32x4*)(myrow + (112 ^ sx)) = (u32x4){0u, 0u, 0u, 0u};

    const int asx = (l16 & 7) << 4;   // swizzle for rows selected by l16

    // MFMA: 4 M-tiles x 2 N-tiles x 2 K-tiles x 2 terms; m scatter back to LDS
#pragma unroll
    for (int mt = 0; mt < 4; ++mt) {
        const char* arow = wbase + (mt * 16 + l16) * 128;
        const bf16x8 a0 = *(const bf16x8*)(arow + ((lq * 16) ^ asx));       // k 0..31
        const bf16x8 a1 = *(const bf16x8*)(arow + ((64 + lq * 16) ^ asx));  // k 32..63
        f32x4 acc0 = {0.f, 0.f, 0.f, 0.f}, acc1 = {0.f, 0.f, 0.f, 0.f};
        acc0 = __builtin_amdgcn_mfma_f32_16x16x32_bf16(a0, Bf[0][0][0], acc0, 0, 0, 0);
        acc0 = __builtin_amdgcn_mfma_f32_16x16x32_bf16(a1, Bf[0][1][0], acc0, 0, 0, 0);
        acc0 = __builtin_amdgcn_mfma_f32_16x16x32_bf16(a0, Bf[1][0][0], acc0, 0, 0, 0);
        acc0 = __builtin_amdgcn_mfma_f32_16x16x32_bf16(a1, Bf[1][1][0], acc0, 0, 0, 0);
        acc1 = __builtin_amdgcn_mfma_f32_16x16x32_bf16(a0, Bf[0][0][1], acc1, 0, 0, 0);
        acc1 = __builtin_amdgcn_mfma_f32_16x16x32_bf16(a1, Bf[0][1][1], acc1, 0, 0, 0);
        acc1 = __builtin_amdgcn_mfma_f32_16x16x32_bf16(a0, Bf[1][0][1], acc1, 0, 0, 0);
        acc1 = __builtin_amdgcn_mfma_f32_16x16x32_bf16(a1, Bf[1][1][1], acc1, 0, 0, 0);
        // C: row(px) = mt*16 + lq*4 + r, col(j) = nt*16 + l16 -> byte 4j
#pragma unroll
        for (int r = 0; r < 4; ++r) {
            char* rowp = wbase + (mt * 16 + lq * 4 + r) * 128;
            const int rsw = ((lq * 4 + r) & 7) << 4;
            const int nb0 = l16 * 4;         // j = l16       (nt=0)
            const int nb1 = 64 + l16 * 4;    // j = 16 + l16  (nt=1)
            *(float*)(rowp + ((nb0 & 0x70) ^ rsw) + (nb0 & 15)) = acc0[r];
            *(float*)(rowp + ((nb1 & 0x70) ^ rsw) + (nb1 & 15)) = acc1[r];
        }
    }

    // read back this pixel's 27 logits (swizzled b128 x7)
    f32x4 mv[7];
#pragma unroll
    for (int q = 0; q < 7; ++q)
        mv[q] = *(const f32x4*)(myrow + ((q * 16) ^ sx));

    // softmax (base-2, pre-scaled, no max-sub) + convex combine
    const size_t ob = ((size_t)(bidx * HH + hrow) * (WW * 3)) + (size_t)wcol * 3;
#pragma unroll
    for (int v = 0; v < 3; ++v) {
        float ssum = 0.0f, acc = 0.0f;
#pragma unroll
        for (int k = 0; k < 9; ++k) {
            const int j = k * 3 + v;
            const float e = __builtin_amdgcn_exp2f(mv[j >> 2][j & 3]);
            ssum += e;
            acc = fmaf(xv[k], e, acc);
        }
        out[ob + v] = acc * __builtin_amdgcn_rcpf(ssum);
    }
}

extern "C" void kernel_launch(void* const* d_in, const int* in_sizes, int n_in,
                              void* d_out, int out_size, void* d_ws, size_t ws_size,
                              hipStream_t stream) {
    // setup_inputs order: x, target_h, target_w, w1, b1, alpha, w2, b2
    const float* x     = (const float*)d_in[0];
    const float* w1    = (const float*)d_in[3];
    const float* b1    = (const float*)d_in[4];
    const float* alpha = (const float*)d_in[5];
    const float* w2    = (const float*)d_in[6];
    const float* b2    = (const float*)d_in[7];
    float* out = (float*)d_out;
    __hip_bfloat16* wsB = (__hip_bfloat16*)d_ws;   // 2*32*64 bf16 = 8 KB

    hipLaunchKernelGGL(prep_B, dim3(8), dim3(256), 0, stream, w1, b1, alpha, w2, b2, wsB);

    const int total  = BB * HH * WW;
    const int blocks = total / 256;   // 16384
    hipLaunchKernelGGL(convex_upsample_mfma, dim3(blocks), dim3(256), 0, stream,
                       x, w1, b1, wsB, out);
}